// Round 1
// baseline (210.181 us; speedup 1.0000x reference)
//
#include <hip/hip_runtime.h>
#include <hip/hip_bf16.h>

#define BB 2
#define SS 2048
#define DD 1024
#define HH 16
#define HD 64

typedef __attribute__((ext_vector_type(8))) short bf16x8;
typedef __attribute__((ext_vector_type(4))) float f32x4;

// round-to-nearest-even f32 -> bf16 (inputs finite)
__device__ __forceinline__ unsigned short f2bf(float f) {
  unsigned int u = __float_as_uint(f);
  return (unsigned short)((u + 0x7FFFu + ((u >> 16) & 1u)) >> 16);
}

// 2^x via hardware v_exp_f32
__device__ __forceinline__ float fast_exp2(float x) {
#if __has_builtin(__builtin_amdgcn_exp2f)
  return __builtin_amdgcn_exp2f(x);
#else
  return __expf(x * 0.6931471805599453f);
#endif
}

__device__ __forceinline__ void async_copy16(const unsigned short* gp, unsigned short* lp) {
  __builtin_amdgcn_global_load_lds(
      (const __attribute__((address_space(1))) unsigned int*)gp,
      (__attribute__((address_space(3))) unsigned int*)lp, 16, 0, 0);
}

// gfx950 cross-lane register swaps (VALU, not DS pipe).
// permlane32_swap: a' = {a.lo32, b.lo32}, b' = {a.hi32, b.hi32}
//   == exchange register-index-bit <-> lane-bit5.
// permlane16_swap: per 32-half, a' = {a.row0, b.row0}, b' = {a.row1, b.row1}
//   == exchange register-index-bit <-> lane-bit4.
__device__ __forceinline__ void pl32_swap(unsigned& a, unsigned& b) {
#if __has_builtin(__builtin_amdgcn_permlane32_swap)
  auto r = __builtin_amdgcn_permlane32_swap(a, b, false, false);
  a = r[0];
  b = r[1];
#else
  asm volatile("v_permlane32_swap_b32 %0, %1" : "+v"(a), "+v"(b));
#endif
}
__device__ __forceinline__ void pl16_swap(unsigned& a, unsigned& b) {
#if __has_builtin(__builtin_amdgcn_permlane16_swap)
  auto r = __builtin_amdgcn_permlane16_swap(a, b, false, false);
  a = r[0];
  b = r[1];
#else
  asm volatile("v_permlane16_swap_b32 %0, %1" : "+v"(a), "+v"(b));
#endif
}

// ---------------------------------------------------------------------------
// Fused prep: blocks [0,4096) convert x -> bf16; blocks [4096,8192) transpose
// one of the 4 weight matrices (1024 32x32 tiles each) to bf16 [N][K].
// ---------------------------------------------------------------------------
__global__ __launch_bounds__(256) void prep_kernel(
    const float* __restrict__ x, unsigned short* __restrict__ xb,
    const float* __restrict__ W0, unsigned short* __restrict__ T0,
    const float* __restrict__ W1, unsigned short* __restrict__ T1,
    const float* __restrict__ W2, unsigned short* __restrict__ T2,
    const float* __restrict__ W3, unsigned short* __restrict__ T3) {
  const int blk = blockIdx.x;
  const int t = threadIdx.x;
  if (blk < 4096) {
    int i = blk * 1024 + t * 4;
    float4 v = *(const float4*)(x + i);
    ushort4 u;
    u.x = f2bf(v.x); u.y = f2bf(v.y); u.z = f2bf(v.z); u.w = f2bf(v.w);
    *(ushort4*)(xb + i) = u;
    return;
  }
  const int j = blk - 4096;
  const int jw = j >> 10;          // which weight
  const int tb = j & 1023;
  const float* W = jw == 0 ? W0 : (jw == 1 ? W1 : (jw == 2 ? W2 : W3));
  unsigned short* T = jw == 0 ? T0 : (jw == 1 ? T1 : (jw == 2 ? T2 : T3));
  __shared__ float tile[32][33];
  int k0 = (tb & 31) * 32, n0 = (tb >> 5) * 32;
  int c = t & 31, r0 = t >> 5;
#pragma unroll
  for (int i = 0; i < 4; ++i) {
    int r = r0 + i * 8;
    tile[r][c] = W[(size_t)(k0 + r) * DD + n0 + c];
  }
  __syncthreads();
#pragma unroll
  for (int i = 0; i < 4; ++i) {
    int r = r0 + i * 8;
    T[(size_t)(n0 + r) * DD + k0 + c] = f2bf(tile[c][r]);
  }
}

// ---------------------------------------------------------------------------
// bf16 MFMA GEMM core (m97 single-buffer, BK=32): D = A[M,K]@B^T[N,K] + bias
// STORE=0: fp32 out [M][DD]
// STORE=1: bf16 out [B,H,S,HD], value scaled (Q: 0.125*log2e, K: 1)
// STORE=2: bf16 out [B,H,HD,S] (V transposed), LDS-transposed coalesced store
// ---------------------------------------------------------------------------
template <int STORE>
__device__ __forceinline__ void gemm_core(
    const unsigned short* __restrict__ A, const unsigned short* __restrict__ BT,
    const float* __restrict__ bias, void* __restrict__ outp, float scale,
    int bm, int bn) {
  const int t = threadIdx.x;
  const int w = t >> 6;
  const int l = t & 63;
  const int wm = (w >> 1) * 64;
  const int wn = (w & 1) * 64;

  __shared__ __align__(16) unsigned short As[128 * 32];
  __shared__ __align__(16) unsigned short Bs[128 * 32];

  f32x4 acc[4][4];
#pragma unroll
  for (int i = 0; i < 4; ++i)
#pragma unroll
    for (int j = 0; j < 4; ++j) acc[i][j] = (f32x4)0.f;

  const int fr = l & 15;
  const int kg = (l >> 4) * 8;

  for (int k0 = 0; k0 < DD; k0 += 32) {
    __syncthreads();
#pragma unroll
    for (int c = 0; c < 2; ++c) {
      int e = (w * 2 + c) * 512 + l * 8;
      int row = e >> 5, kk = e & 31;
      async_copy16(A + (size_t)(bm + row) * DD + k0 + kk, As + (w * 2 + c) * 512);
      async_copy16(BT + (size_t)(bn + row) * DD + k0 + kk, Bs + (w * 2 + c) * 512);
    }
    __syncthreads();

    bf16x8 af[4], bfr[4];
#pragma unroll
    for (int i = 0; i < 4; ++i)
      af[i] = *(const bf16x8*)(As + (wm + i * 16 + fr) * 32 + kg);
#pragma unroll
    for (int j = 0; j < 4; ++j)
      bfr[j] = *(const bf16x8*)(Bs + (wn + j * 16 + fr) * 32 + kg);
#pragma unroll
    for (int i = 0; i < 4; ++i)
#pragma unroll
      for (int j = 0; j < 4; ++j)
        acc[i][j] = __builtin_amdgcn_mfma_f32_16x16x32_bf16(af[i], bfr[j], acc[i][j], 0, 0, 0);
  }

  const int col_l = l & 15;
  const int row_l = (l >> 4) * 4;

  if (STORE == 2) {
    // Transpose 128x128 C tile via LDS (4 passes of 32 n-cols), then store
    // VbT[(b*HH+h)*HD+hd][s] with 256 B contiguous runs along s.
    unsigned short* out = (unsigned short*)outp;
    unsigned int* T = (unsigned int*)As;  // 2048 dwords
    const int b_ = bm >> 11;
    const int srow0 = bm & 2047;          // within-batch S offset
#pragma unroll
    for (int p = 0; p < 4; ++p) {
      __syncthreads();  // As free (K-loop done / previous pass read done)
      if ((w & 1) == (p >> 1)) {
        const int jt0 = (p & 1) * 2;
#pragma unroll
        for (int jj = 0; jj < 2; ++jj) {
          int jt = jt0 + jj;
          int n_p = jj * 16 + col_l;          // n within pass [0,32)
          float bv = bias[bn + p * 32 + n_p];
#pragma unroll
          for (int i = 0; i < 4; ++i) {
            int m0 = wm + i * 16 + row_l;     // even
#pragma unroll
            for (int pr = 0; pr < 2; ++pr) {
              unsigned int val =
                  (unsigned int)f2bf(acc[i][jt][2 * pr] + bv) |
                  ((unsigned int)f2bf(acc[i][jt][2 * pr + 1] + bv) << 16);
              int m = m0 + 2 * pr;
              T[n_p * 64 + (((m >> 1)) ^ ((n_p & 7) << 2))] = val;
            }
          }
        }
      }
      __syncthreads();
#pragma unroll
      for (int c = 0; c < 2; ++c) {
        int q = t + c * 256;
        int n_p = q >> 4, cpos = q & 15;
        uint4 v = *(const uint4*)(T + n_p * 64 + ((cpos * 4) ^ ((n_p & 7) << 2)));
        int n_glob = bn + p * 32 + n_p;
        int h_ = n_glob >> 6, hd_ = n_glob & 63;
        *(uint4*)(out + ((size_t)((b_ * HH + h_) * HD + hd_)) * SS + srow0 + cpos * 8) = v;
      }
    }
    return;
  }

#pragma unroll
  for (int i = 0; i < 4; ++i) {
    int m_base = bm + wm + i * 16 + row_l;
#pragma unroll
    for (int j = 0; j < 4; ++j) {
      int n = bn + wn + j * 16 + col_l;
      float bv = bias[n];
      if (STORE == 0) {
        float* out = (float*)outp;
#pragma unroll
        for (int r = 0; r < 4; ++r)
          out[(size_t)(m_base + r) * DD + n] = acc[i][j][r] + bv;
      } else {
        unsigned short* out = (unsigned short*)outp;
        int h_ = n >> 6, hd_ = n & 63;
#pragma unroll
        for (int r = 0; r < 4; ++r) {
          int m = m_base + r;
          int b_ = m >> 11, s_ = m & 2047;
          out[(((size_t)(b_ * HH + h_) * SS) + s_) * HD + hd_] =
              f2bf((acc[i][j][r] + bv) * scale);
        }
      }
    }
  }
}

// Fused QKV projection, 768 blocks, XCD-swizzled: all 24 (which,bn) blocks of
// one A-tile land on ONE XCD (i%8 = XCD round-robin) -> A-tile read once into
// that XCD's L2, 24x reuse; LLC A-traffic /3.
__global__ __launch_bounds__(256) void qkv_gemm_mfma(
    const unsigned short* __restrict__ A,
    const unsigned short* __restrict__ WqT, const unsigned short* __restrict__ WkT,
    const unsigned short* __restrict__ WvT,
    const float* __restrict__ bq, const float* __restrict__ bk,
    const float* __restrict__ bv,
    unsigned short* __restrict__ Qo, unsigned short* __restrict__ Ko,
    unsigned short* __restrict__ VTo) {
  const int i = blockIdx.x;
  const int xcd = i & 7;
  const int slot = i >> 3;            // 0..95
  const int bm = (xcd + 8 * (slot / 24)) * 128;
  const int c = slot % 24;
  const int which = c >> 3;
  const int bn = (c & 7) * 128;
  if (which == 0)
    gemm_core<1>(A, WqT, bq, (void*)Qo, 0.18033688011112042f, bm, bn);
  else if (which == 1)
    gemm_core<1>(A, WkT, bk, (void*)Ko, 1.0f, bm, bn);
  else
    gemm_core<2>(A, WvT, bv, (void*)VTo, 1.0f, bm, bn);
}

// output projection, 256 blocks, XCD-swizzled likewise (8 bn per bm on one XCD)
__global__ __launch_bounds__(256) void out_gemm_mfma(
    const unsigned short* __restrict__ A, const unsigned short* __restrict__ WoT,
    const float* __restrict__ bo, float* __restrict__ out) {
  const int i = blockIdx.x;
  const int xcd = i & 7;
  const int slot = i >> 3;            // 0..31
  const int bm = (xcd + 8 * (slot >> 3)) * 128;
  const int bn = (slot & 7) * 128;
  gemm_core<0>(A, WoT, bo, (void*)out, 1.0f, bm, bn);
}

// ---------------------------------------------------------------------------
// MFMA flash attention v7: v6 structure (Q-tile 128, 4 waves, dbuf K/V) but
// the P C-layout->B-layout conversion is now done ENTIRELY IN REGISTERS via
// gfx950 v_permlane{32,16}_swap_b32 (VALU) instead of the LDS scratch
// round-trip (8 ds_write_b64 + 4 ds_read_b128 per wave/iter). R10 showed the
// kernel is DS-pipe bound: this cuts DS ops/wave-iter 28 -> 16 and removes an
// lgkmcnt-serialized LDS round-trip from every K-tile iteration.
//
// Layout algebra: after S^T = K Q^T, lane (g,ln) holds packed dwords
// Sd[mt][p] = keys mt*16+4g+2p..+1 at q=nt*16+ln. Two reg-bit<->lane-bit
// exchanges (mt-bit0 <-> lane-bit5, then that slot <-> lane-bit4) place
// Sd[2*kb+i1][i0] = B-frag dword 2*i1+i0 = keys kb*32+g*8+2i..+1 -- exactly
// what PV's mfma B-operand needs.
// ---------------------------------------------------------------------------
__global__ __launch_bounds__(256) void flash_attn_mfma(
    const unsigned short* __restrict__ Q,   // [B,H,S,HD] bf16 (pre-scaled)
    const unsigned short* __restrict__ K,   // [B,H,S,HD] bf16
    const unsigned short* __restrict__ VT,  // [B,H,HD,S] bf16
    unsigned short* __restrict__ ctx) {     // [B,S,D] bf16
  const int bh = blockIdx.x;
  const int qt = blockIdx.y;
  const int b  = bh >> 4;
  const int h  = bh & 15;
  const int t  = threadIdx.x;
  const int w  = t >> 6;   // wave 0..3
  const int l  = t & 63;
  const int g  = l >> 4;   // lane group 0..3
  const int ln = l & 15;   // q index within n-tile

  const unsigned short* Qp = Q + ((size_t)bh * SS + (size_t)qt * 128 + w * 32) * HD;
  const unsigned short* Kp = K + (size_t)bh * SS * HD;
  const unsigned short* Vp = VT + (size_t)bh * HD * SS;

  __shared__ __align__(16) unsigned short Ks[2][64 * 64];  // [key][hd], swizzled
  __shared__ __align__(16) unsigned short Vs[2][64 * 64];  // [hd][key], swizzled

  // Q as B-operand fragments: qf[nt][kb], n=ln, k = kb*32 + g*8 + j
  bf16x8 qf[2][2];
#pragma unroll
  for (int nt = 0; nt < 2; ++nt)
#pragma unroll
    for (int kb = 0; kb < 2; ++kb)
      qf[nt][kb] = *(const bf16x8*)(Qp + (nt * 16 + ln) * HD + kb * 32 + g * 8);

  f32x4 o[2][4];
#pragma unroll
  for (int nt = 0; nt < 2; ++nt)
#pragma unroll
    for (int mt = 0; mt < 4; ++mt) o[nt][mt] = (f32x4)0.f;
  float rs[2] = {0.f, 0.f};

  // staging: 512 chunks of 16 B per tile; 2 per thread for K and V each
  auto stage = [&](int kt, int half) {
#pragma unroll
    for (int j = 0; j < 2; ++j) {
      int c = (w * 2 + j) * 64 + l;
      int row = c >> 3, cc = c & 7;
      int gcc = cc ^ (row & 7);
      async_copy16(Kp + (size_t)(kt * 64 + row) * HD + gcc * 8,
                   &Ks[half][(w * 2 + j) * 512]);
      async_copy16(Vp + (size_t)row * SS + kt * 64 + gcc * 8,
                   &Vs[half][(w * 2 + j) * 512]);
    }
  };

  stage(0, 0);
  for (int kt = 0; kt < SS / 64; ++kt) {
    const int half = kt & 1;
    __syncthreads();  // drains vmcnt -> buf[half] ready; buf[half^1] free
    if (kt + 1 < SS / 64) stage(kt + 1, half ^ 1);

    // --- S^T = K Q^T : st[nt][mt][r] = S[key = mt*16+4g+r][q = nt*16+ln]
    f32x4 st[2][4];
#pragma unroll
    for (int nt = 0; nt < 2; ++nt)
#pragma unroll
      for (int mt = 0; mt < 4; ++mt) st[nt][mt] = (f32x4)0.f;
#pragma unroll
    for (int kb = 0; kb < 2; ++kb)
#pragma unroll
      for (int mt = 0; mt < 4; ++mt) {
        int row = mt * 16 + ln;
        bf16x8 ka = *(const bf16x8*)(&Ks[half][row * 64 + (((kb * 4 + g) ^ (row & 7)) * 8)]);
        st[0][mt] = __builtin_amdgcn_mfma_f32_16x16x32_bf16(ka, qf[0][kb], st[0][mt], 0, 0, 0);
        st[1][mt] = __builtin_amdgcn_mfma_f32_16x16x32_bf16(ka, qf[1][kb], st[1][mt], 0, 0, 0);
      }

    // --- p = exp2(s'); pack bf16 pairs in-register; redistribute via
    // permlane swaps (no LDS, no DS-pipe traffic).
    unsigned Sd[2][4][2];  // [nt][mt][p]: keys mt*16+4g+2p..+1, q=nt*16+ln
#pragma unroll
    for (int nt = 0; nt < 2; ++nt) {
#pragma unroll
      for (int mt = 0; mt < 4; ++mt) {
        float p0 = fast_exp2(st[nt][mt][0]);
        float p1 = fast_exp2(st[nt][mt][1]);
        float p2 = fast_exp2(st[nt][mt][2]);
        float p3 = fast_exp2(st[nt][mt][3]);
        Sd[nt][mt][0] = __builtin_amdgcn_perm(__float_as_uint(p1), __float_as_uint(p0),
                                              0x07060302u);  // lo=p0,hi=p1
        Sd[nt][mt][1] = __builtin_amdgcn_perm(__float_as_uint(p3), __float_as_uint(p2),
                                              0x07060302u);
        rs[nt] += (p0 + p1) + (p2 + p3);
      }
      // step 1: exchange mt-bit0 <-> lane-bit5 (data (m0,b5)=(x,y) -> (y,x))
#pragma unroll
      for (int m1 = 0; m1 < 2; ++m1)
#pragma unroll
        for (int p = 0; p < 2; ++p)
          pl32_swap(Sd[nt][2 * m1][p], Sd[nt][2 * m1 + 1][p]);
      // step 2: exchange (former lane-bit5, now in reg slot) <-> lane-bit4
#pragma unroll
      for (int m1 = 0; m1 < 2; ++m1)
#pragma unroll
        for (int p = 0; p < 2; ++p)
          pl16_swap(Sd[nt][2 * m1][p], Sd[nt][2 * m1 + 1][p]);
    }
    // Now Sd[nt][2*kb+i1][i0] = frag dword i=2*i1+i0: keys kb*32+g*8+2i..+1.

    // --- O^T += V^T P^T : P B-frags straight from registers
#pragma unroll
    for (int kb = 0; kb < 2; ++kb) {
      bf16x8 pbv[2];
#pragma unroll
      for (int nt = 0; nt < 2; ++nt) {
        union { unsigned u[4]; bf16x8 v; } c;
        c.u[0] = Sd[nt][2 * kb][0];
        c.u[1] = Sd[nt][2 * kb][1];
        c.u[2] = Sd[nt][2 * kb + 1][0];
        c.u[3] = Sd[nt][2 * kb + 1][1];
        pbv[nt] = c.v;
      }
#pragma unroll
      for (int mt = 0; mt < 4; ++mt) {
        int row = mt * 16 + ln;
        bf16x8 va = *(const bf16x8*)(&Vs[half][row * 64 + (((kb * 4 + g) ^ (row & 7)) * 8)]);
        o[0][mt] = __builtin_amdgcn_mfma_f32_16x16x32_bf16(va, pbv[0], o[0][mt], 0, 0, 0);
        o[1][mt] = __builtin_amdgcn_mfma_f32_16x16x32_bf16(va, pbv[1], o[1][mt], 0, 0, 0);
      }
    }
  }

  // --- epilogue: reduce l over lane groups, normalize, store bf16 ctx
#pragma unroll
  for (int nt = 0; nt < 2; ++nt) {
    float lsum = rs[nt];
    lsum += __shfl_xor(lsum, 16, 64);
    lsum += __shfl_xor(lsum, 32, 64);
    float inv = 1.f / lsum;
    int srow = qt * 128 + w * 32 + nt * 16 + ln;
    unsigned short* cb = ctx + (size_t)(b * SS + srow) * DD + h * HD;
#pragma unroll
    for (int mt = 0; mt < 4; ++mt) {
      ushort4 u4;
      u4.x = f2bf(o[nt][mt][0] * inv);
      u4.y = f2bf(o[nt][mt][1] * inv);
      u4.z = f2bf(o[nt][mt][2] * inv);
      u4.w = f2bf(o[nt][mt][3] * inv);
      *(ushort4*)(cb + mt * 16 + 4 * g) = u4;
    }
  }
}

// ---------------------------------------------------------------------------
extern "C" void kernel_launch(void* const* d_in, const int* in_sizes, int n_in,
                              void* d_out, int out_size, void* d_ws, size_t ws_size,
                              hipStream_t stream) {
  const float* x  = (const float*)d_in[0];
  const float* Wq = (const float*)d_in[1];
  const float* bq = (const float*)d_in[2];
  const float* Wk = (const float*)d_in[3];
  const float* bk = (const float*)d_in[4];
  const float* Wv = (const float*)d_in[5];
  const float* bv = (const float*)d_in[6];
  const float* Wo = (const float*)d_in[7];
  const float* bo = (const float*)d_in[8];
  float* out = (float*)d_out;

  const size_t ELEMS = (size_t)BB * SS * DD;  // 4,194,304
  char* ws = (char*)d_ws;
  unsigned short* xb   = (unsigned short*)ws;  ws += ELEMS * 2;
  unsigned short* WqT  = (unsigned short*)ws;  ws += (size_t)DD * DD * 2;
  unsigned short* WkT  = (unsigned short*)ws;  ws += (size_t)DD * DD * 2;
  unsigned short* WvT  = (unsigned short*)ws;  ws += (size_t)DD * DD * 2;
  unsigned short* WoT  = (unsigned short*)ws;  ws += (size_t)DD * DD * 2;
  unsigned short* Qb   = (unsigned short*)ws;  ws += ELEMS * 2;
  unsigned short* Kb   = (unsigned short*)ws;  ws += ELEMS * 2;
  unsigned short* VbT  = (unsigned short*)ws;  ws += ELEMS * 2;
  unsigned short* ctxb = (unsigned short*)ws;  ws += ELEMS * 2;

  // fused prep: x->bf16 (4096 blocks) + 4 weight transposes (4096 blocks)
  prep_kernel<<<8192, 256, 0, stream>>>(x, xb, Wq, WqT, Wk, WkT, Wv, WvT, Wo, WoT);

  qkv_gemm_mfma<<<768, 256, 0, stream>>>(xb, WqT, WkT, WvT, bq, bk, bv,
                                         Qb, Kb, VbT);

  dim3 attn_grid(BB * HH, SS / 128);           // (32, 16) = 512 blocks
  flash_attn_mfma<<<attn_grid, 256, 0, stream>>>(Qb, Kb, VbT, ctxb);

  out_gemm_mfma<<<256, 256, 0, stream>>>(ctxb, WoT, bo, out);
}

// Round 2
// 201.149 us; speedup vs baseline: 1.0449x; 1.0449x over previous
//
#include <hip/hip_runtime.h>
#include <hip/hip_bf16.h>

#define BB 2
#define SS 2048
#define DD 1024
#define HH 16
#define HD 64

typedef __attribute__((ext_vector_type(8))) short bf16x8;
typedef __attribute__((ext_vector_type(4))) float f32x4;

// round-to-nearest-even f32 -> bf16 (inputs finite)
__device__ __forceinline__ unsigned short f2bf(float f) {
  unsigned int u = __float_as_uint(f);
  return (unsigned short)((u + 0x7FFFu + ((u >> 16) & 1u)) >> 16);
}

// 2^x via hardware v_exp_f32
__device__ __forceinline__ float fast_exp2(float x) {
#if __has_builtin(__builtin_amdgcn_exp2f)
  return __builtin_amdgcn_exp2f(x);
#else
  return __expf(x * 0.6931471805599453f);
#endif
}

__device__ __forceinline__ void async_copy16(const unsigned short* gp, unsigned short* lp) {
  __builtin_amdgcn_global_load_lds(
      (const __attribute__((address_space(1))) unsigned int*)gp,
      (__attribute__((address_space(3))) unsigned int*)lp, 16, 0, 0);
}

// gfx950 cross-lane register swaps (VALU, not DS pipe).
__device__ __forceinline__ void pl32_swap(unsigned& a, unsigned& b) {
#if __has_builtin(__builtin_amdgcn_permlane32_swap)
  auto r = __builtin_amdgcn_permlane32_swap(a, b, false, false);
  a = r[0];
  b = r[1];
#else
  asm volatile("v_permlane32_swap_b32 %0, %1" : "+v"(a), "+v"(b));
#endif
}
__device__ __forceinline__ void pl16_swap(unsigned& a, unsigned& b) {
#if __has_builtin(__builtin_amdgcn_permlane16_swap)
  auto r = __builtin_amdgcn_permlane16_swap(a, b, false, false);
  a = r[0];
  b = r[1];
#else
  asm volatile("v_permlane16_swap_b32 %0, %1" : "+v"(a), "+v"(b));
#endif
}

// ---------------------------------------------------------------------------
// Fused prep: blocks [0,4096) convert x -> bf16; blocks [4096,8192) transpose
// one of the 4 weight matrices (1024 32x32 tiles each) to bf16 [N][K].
// ---------------------------------------------------------------------------
__global__ __launch_bounds__(256) void prep_kernel(
    const float* __restrict__ x, unsigned short* __restrict__ xb,
    const float* __restrict__ W0, unsigned short* __restrict__ T0,
    const float* __restrict__ W1, unsigned short* __restrict__ T1,
    const float* __restrict__ W2, unsigned short* __restrict__ T2,
    const float* __restrict__ W3, unsigned short* __restrict__ T3) {
  const int blk = blockIdx.x;
  const int t = threadIdx.x;
  if (blk < 4096) {
    int i = blk * 1024 + t * 4;
    float4 v = *(const float4*)(x + i);
    ushort4 u;
    u.x = f2bf(v.x); u.y = f2bf(v.y); u.z = f2bf(v.z); u.w = f2bf(v.w);
    *(ushort4*)(xb + i) = u;
    return;
  }
  const int j = blk - 4096;
  const int jw = j >> 10;          // which weight
  const int tb = j & 1023;
  const float* W = jw == 0 ? W0 : (jw == 1 ? W1 : (jw == 2 ? W2 : W3));
  unsigned short* T = jw == 0 ? T0 : (jw == 1 ? T1 : (jw == 2 ? T2 : T3));
  __shared__ float tile[32][33];
  int k0 = (tb & 31) * 32, n0 = (tb >> 5) * 32;
  int c = t & 31, r0 = t >> 5;
#pragma unroll
  for (int i = 0; i < 4; ++i) {
    int r = r0 + i * 8;
    tile[r][c] = W[(size_t)(k0 + r) * DD + n0 + c];
  }
  __syncthreads();
#pragma unroll
  for (int i = 0; i < 4; ++i) {
    int r = r0 + i * 8;
    T[(size_t)(n0 + r) * DD + k0 + c] = f2bf(tile[c][r]);
  }
}

// ---------------------------------------------------------------------------
// bf16 MFMA GEMM core (m97 single-buffer, BK=32): D = A[M,K]@B^T[N,K] + bias
// STORE=0: fp32 out [M][DD]
// STORE=1: bf16 out [B,H,S,HD], value scaled (Q: 0.125*log2e, K: 1)
// STORE=2: bf16 out [B,H,HD,S] (V transposed), LDS-transposed coalesced store
// ---------------------------------------------------------------------------
template <int STORE>
__device__ __forceinline__ void gemm_core(
    const unsigned short* __restrict__ A, const unsigned short* __restrict__ BT,
    const float* __restrict__ bias, void* __restrict__ outp, float scale,
    int bm, int bn) {
  const int t = threadIdx.x;
  const int w = t >> 6;
  const int l = t & 63;
  const int wm = (w >> 1) * 64;
  const int wn = (w & 1) * 64;

  __shared__ __align__(16) unsigned short As[128 * 32];
  __shared__ __align__(16) unsigned short Bs[128 * 32];

  f32x4 acc[4][4];
#pragma unroll
  for (int i = 0; i < 4; ++i)
#pragma unroll
    for (int j = 0; j < 4; ++j) acc[i][j] = (f32x4)0.f;

  const int fr = l & 15;
  const int kg = (l >> 4) * 8;

  for (int k0 = 0; k0 < DD; k0 += 32) {
    __syncthreads();
#pragma unroll
    for (int c = 0; c < 2; ++c) {
      int e = (w * 2 + c) * 512 + l * 8;
      int row = e >> 5, kk = e & 31;
      async_copy16(A + (size_t)(bm + row) * DD + k0 + kk, As + (w * 2 + c) * 512);
      async_copy16(BT + (size_t)(bn + row) * DD + k0 + kk, Bs + (w * 2 + c) * 512);
    }
    __syncthreads();

    bf16x8 af[4], bfr[4];
#pragma unroll
    for (int i = 0; i < 4; ++i)
      af[i] = *(const bf16x8*)(As + (wm + i * 16 + fr) * 32 + kg);
#pragma unroll
    for (int j = 0; j < 4; ++j)
      bfr[j] = *(const bf16x8*)(Bs + (wn + j * 16 + fr) * 32 + kg);
#pragma unroll
    for (int i = 0; i < 4; ++i)
#pragma unroll
      for (int j = 0; j < 4; ++j)
        acc[i][j] = __builtin_amdgcn_mfma_f32_16x16x32_bf16(af[i], bfr[j], acc[i][j], 0, 0, 0);
  }

  const int col_l = l & 15;
  const int row_l = (l >> 4) * 4;

  if (STORE == 2) {
    // Transpose 128x128 C tile via LDS (4 passes of 32 n-cols), then store
    // VbT[(b*HH+h)*HD+hd][s] with 256 B contiguous runs along s.
    unsigned short* out = (unsigned short*)outp;
    unsigned int* T = (unsigned int*)As;  // 2048 dwords
    const int b_ = bm >> 11;
    const int srow0 = bm & 2047;          // within-batch S offset
#pragma unroll
    for (int p = 0; p < 4; ++p) {
      __syncthreads();  // As free (K-loop done / previous pass read done)
      if ((w & 1) == (p >> 1)) {
        const int jt0 = (p & 1) * 2;
#pragma unroll
        for (int jj = 0; jj < 2; ++jj) {
          int jt = jt0 + jj;
          int n_p = jj * 16 + col_l;          // n within pass [0,32)
          float bv = bias[bn + p * 32 + n_p];
#pragma unroll
          for (int i = 0; i < 4; ++i) {
            int m0 = wm + i * 16 + row_l;     // even
#pragma unroll
            for (int pr = 0; pr < 2; ++pr) {
              unsigned int val =
                  (unsigned int)f2bf(acc[i][jt][2 * pr] + bv) |
                  ((unsigned int)f2bf(acc[i][jt][2 * pr + 1] + bv) << 16);
              int m = m0 + 2 * pr;
              T[n_p * 64 + (((m >> 1)) ^ ((n_p & 7) << 2))] = val;
            }
          }
        }
      }
      __syncthreads();
#pragma unroll
      for (int c = 0; c < 2; ++c) {
        int q = t + c * 256;
        int n_p = q >> 4, cpos = q & 15;
        uint4 v = *(const uint4*)(T + n_p * 64 + ((cpos * 4) ^ ((n_p & 7) << 2)));
        int n_glob = bn + p * 32 + n_p;
        int h_ = n_glob >> 6, hd_ = n_glob & 63;
        *(uint4*)(out + ((size_t)((b_ * HH + h_) * HD + hd_)) * SS + srow0 + cpos * 8) = v;
      }
    }
    return;
  }

#pragma unroll
  for (int i = 0; i < 4; ++i) {
    int m_base = bm + wm + i * 16 + row_l;
#pragma unroll
    for (int j = 0; j < 4; ++j) {
      int n = bn + wn + j * 16 + col_l;
      float bv = bias[n];
      if (STORE == 0) {
        float* out = (float*)outp;
#pragma unroll
        for (int r = 0; r < 4; ++r)
          out[(size_t)(m_base + r) * DD + n] = acc[i][j][r] + bv;
      } else {
        unsigned short* out = (unsigned short*)outp;
        int h_ = n >> 6, hd_ = n & 63;
#pragma unroll
        for (int r = 0; r < 4; ++r) {
          int m = m_base + r;
          int b_ = m >> 11, s_ = m & 2047;
          out[(((size_t)(b_ * HH + h_) * SS) + s_) * HD + hd_] =
              f2bf((acc[i][j][r] + bv) * scale);
        }
      }
    }
  }
}

// Fused QKV projection, 768 blocks, XCD-swizzled: all 24 (which,bn) blocks of
// one A-tile land on ONE XCD (i%8 = XCD round-robin) -> A-tile read once into
// that XCD's L2, 24x reuse; LLC A-traffic /3.
__global__ __launch_bounds__(256) void qkv_gemm_mfma(
    const unsigned short* __restrict__ A,
    const unsigned short* __restrict__ WqT, const unsigned short* __restrict__ WkT,
    const unsigned short* __restrict__ WvT,
    const float* __restrict__ bq, const float* __restrict__ bk,
    const float* __restrict__ bv,
    unsigned short* __restrict__ Qo, unsigned short* __restrict__ Ko,
    unsigned short* __restrict__ VTo) {
  const int i = blockIdx.x;
  const int xcd = i & 7;
  const int slot = i >> 3;            // 0..95
  const int bm = (xcd + 8 * (slot / 24)) * 128;
  const int c = slot % 24;
  const int which = c >> 3;
  const int bn = (c & 7) * 128;
  if (which == 0)
    gemm_core<1>(A, WqT, bq, (void*)Qo, 0.18033688011112042f, bm, bn);
  else if (which == 1)
    gemm_core<1>(A, WkT, bk, (void*)Ko, 1.0f, bm, bn);
  else
    gemm_core<2>(A, WvT, bv, (void*)VTo, 1.0f, bm, bn);
}

// output projection, 256 blocks, XCD-swizzled likewise (8 bn per bm on one XCD)
__global__ __launch_bounds__(256) void out_gemm_mfma(
    const unsigned short* __restrict__ A, const unsigned short* __restrict__ WoT,
    const float* __restrict__ bo, float* __restrict__ out) {
  const int i = blockIdx.x;
  const int xcd = i & 7;
  const int slot = i >> 3;            // 0..31
  const int bm = (xcd + 8 * (slot >> 3)) * 128;
  const int bn = (slot & 7) * 128;
  gemm_core<0>(A, WoT, bo, (void*)out, 1.0f, bm, bn);
}

// ---------------------------------------------------------------------------
// MFMA flash attention v8: occupancy fix. R1 counters: Occupancy 18%,
// MfmaUtil 22%, bank conflicts 0, HBM 4.5% -> latency-bound at 2 waves/SIMD
// (512 blocks x 4 waves on 256 CUs). v8 keeps the per-wave structure (32
// q-rows, 64-key tiles, permlane P redistribution) but runs 8 waves/block
// (512 thr): waves 0-3 process EVEN key tiles, waves 4-7 ODD key tiles.
// Per-wave iteration count halves; per-CU DS traffic unchanged; LDS 64 KB
// (parity x dbuf x K,V) -> still 2 blocks/CU -> 4 waves/SIMD (2x). One-time
// cross-parity combine of partial o/rs through LDS at the end.
// ---------------------------------------------------------------------------
__global__ __launch_bounds__(512, 4) void flash_attn_mfma(
    const unsigned short* __restrict__ Q,   // [B,H,S,HD] bf16 (pre-scaled)
    const unsigned short* __restrict__ K,   // [B,H,S,HD] bf16
    const unsigned short* __restrict__ VT,  // [B,H,HD,S] bf16
    unsigned short* __restrict__ ctx) {     // [B,S,D] bf16
  const int bh = blockIdx.x;
  const int qt = blockIdx.y;
  const int b  = bh >> 4;
  const int h  = bh & 15;
  const int t  = threadIdx.x;
  const int w  = t >> 6;   // wave 0..7
  const int l  = t & 63;
  const int wg = w & 3;    // q sub-tile 0..3
  const int wh = w >> 2;   // key-tile parity 0/1
  const int g  = l >> 4;   // lane group 0..3
  const int ln = l & 15;   // q index within n-tile

  const unsigned short* Qp = Q + ((size_t)bh * SS + (size_t)qt * 128 + wg * 32) * HD;
  const unsigned short* Kp = K + (size_t)bh * SS * HD;
  const unsigned short* Vp = VT + (size_t)bh * HD * SS;

  __shared__ __align__(16) unsigned short Ks[2][2][64 * 64];  // [parity][dbuf][key][hd] swz
  __shared__ __align__(16) unsigned short Vs[2][2][64 * 64];  // [parity][dbuf][hd][key] swz

  // Q as B-operand fragments: qf[nt][kb], n=ln, k = kb*32 + g*8 + j
  bf16x8 qf[2][2];
#pragma unroll
  for (int nt = 0; nt < 2; ++nt)
#pragma unroll
    for (int kb = 0; kb < 2; ++kb)
      qf[nt][kb] = *(const bf16x8*)(Qp + (nt * 16 + ln) * HD + kb * 32 + g * 8);

  f32x4 o[2][4];
#pragma unroll
  for (int nt = 0; nt < 2; ++nt)
#pragma unroll
    for (int mt = 0; mt < 4; ++mt) o[nt][mt] = (f32x4)0.f;
  float rs[2] = {0.f, 0.f};

  // staging: a key-tile PAIR (2 K-tiles + 2 V-tiles = 32 KB) per block-iter;
  // each tile = 512 x 16 B chunks, 512 threads -> 1 chunk/thread/tile.
  // chunk c = t: per wave the LDS dest is uniform base + lane*16 (HW rule).
  auto stage2 = [&](int kt2, int db) {
    const int c = t;
    const int row = c >> 3, cc = c & 7;
    const int gcc = cc ^ (row & 7);
    const int k0 = kt2 * 128;
    unsigned short* dK0 = &Ks[0][db][w * 512];
    unsigned short* dK1 = &Ks[1][db][w * 512];
    unsigned short* dV0 = &Vs[0][db][w * 512];
    unsigned short* dV1 = &Vs[1][db][w * 512];
    async_copy16(Kp + (size_t)(k0 + row) * HD + gcc * 8, dK0);
    async_copy16(Kp + (size_t)(k0 + 64 + row) * HD + gcc * 8, dK1);
    async_copy16(Vp + (size_t)row * SS + k0 + gcc * 8, dV0);
    async_copy16(Vp + (size_t)row * SS + k0 + 64 + gcc * 8, dV1);
  };

  stage2(0, 0);
  for (int kt2 = 0; kt2 < SS / 128; ++kt2) {
    const int db = kt2 & 1;
    __syncthreads();  // drains vmcnt -> buffers [.,db] ready; [.,db^1] free
    if (kt2 + 1 < SS / 128) stage2(kt2 + 1, db ^ 1);

    const unsigned short* Kst = &Ks[wh][db][0];
    const unsigned short* Vst = &Vs[wh][db][0];

    // --- S^T = K Q^T : st[nt][mt][r] = S[key = mt*16+4g+r][q = nt*16+ln]
    f32x4 st[2][4];
#pragma unroll
    for (int nt = 0; nt < 2; ++nt)
#pragma unroll
      for (int mt = 0; mt < 4; ++mt) st[nt][mt] = (f32x4)0.f;
#pragma unroll
    for (int kb = 0; kb < 2; ++kb)
#pragma unroll
      for (int mt = 0; mt < 4; ++mt) {
        int row = mt * 16 + ln;
        bf16x8 ka = *(const bf16x8*)(&Kst[row * 64 + (((kb * 4 + g) ^ (row & 7)) * 8)]);
        st[0][mt] = __builtin_amdgcn_mfma_f32_16x16x32_bf16(ka, qf[0][kb], st[0][mt], 0, 0, 0);
        st[1][mt] = __builtin_amdgcn_mfma_f32_16x16x32_bf16(ka, qf[1][kb], st[1][mt], 0, 0, 0);
      }

    // --- p = exp2(s'); pack bf16 pairs in-register; redistribute via
    // permlane swaps (no LDS, no DS-pipe traffic).
    unsigned Sd[2][4][2];  // [nt][mt][p]: keys mt*16+4g+2p..+1, q=nt*16+ln
#pragma unroll
    for (int nt = 0; nt < 2; ++nt) {
#pragma unroll
      for (int mt = 0; mt < 4; ++mt) {
        float p0 = fast_exp2(st[nt][mt][0]);
        float p1 = fast_exp2(st[nt][mt][1]);
        float p2 = fast_exp2(st[nt][mt][2]);
        float p3 = fast_exp2(st[nt][mt][3]);
        Sd[nt][mt][0] = __builtin_amdgcn_perm(__float_as_uint(p1), __float_as_uint(p0),
                                              0x07060302u);  // lo=p0,hi=p1
        Sd[nt][mt][1] = __builtin_amdgcn_perm(__float_as_uint(p3), __float_as_uint(p2),
                                              0x07060302u);
        rs[nt] += (p0 + p1) + (p2 + p3);
      }
      // step 1: exchange mt-bit0 <-> lane-bit5
#pragma unroll
      for (int m1 = 0; m1 < 2; ++m1)
#pragma unroll
        for (int p = 0; p < 2; ++p)
          pl32_swap(Sd[nt][2 * m1][p], Sd[nt][2 * m1 + 1][p]);
      // step 2: exchange (former lane-bit5, now in reg slot) <-> lane-bit4
#pragma unroll
      for (int m1 = 0; m1 < 2; ++m1)
#pragma unroll
        for (int p = 0; p < 2; ++p)
          pl16_swap(Sd[nt][2 * m1][p], Sd[nt][2 * m1 + 1][p]);
    }
    // Now Sd[nt][2*kb+i1][i0] = frag dword i=2*i1+i0: keys kb*32+g*8+2i..+1.

    // --- O^T += V^T P^T : P B-frags straight from registers
#pragma unroll
    for (int kb = 0; kb < 2; ++kb) {
      bf16x8 pbv[2];
#pragma unroll
      for (int nt = 0; nt < 2; ++nt) {
        union { unsigned u[4]; bf16x8 v; } c;
        c.u[0] = Sd[nt][2 * kb][0];
        c.u[1] = Sd[nt][2 * kb][1];
        c.u[2] = Sd[nt][2 * kb + 1][0];
        c.u[3] = Sd[nt][2 * kb + 1][1];
        pbv[nt] = c.v;
      }
#pragma unroll
      for (int mt = 0; mt < 4; ++mt) {
        int row = mt * 16 + ln;
        bf16x8 va = *(const bf16x8*)(&Vst[row * 64 + (((kb * 4 + g) ^ (row & 7)) * 8)]);
        o[0][mt] = __builtin_amdgcn_mfma_f32_16x16x32_bf16(va, pbv[0], o[0][mt], 0, 0, 0);
        o[1][mt] = __builtin_amdgcn_mfma_f32_16x16x32_bf16(va, pbv[1], o[1][mt], 0, 0, 0);
      }
    }
  }

  // --- cross-parity combine: wh=1 waves dump partial o/rs to LDS, wh=0 adds.
  __syncthreads();  // all compute done; K/V buffers reusable as scratch
  {
    float* ored = (float*)&Vs[0][0][0];  // 4 regions x 64 lanes x 32 f32 = 32 KB
    float* rred = (float*)&Ks[0][0][0];  // 4 regions x 64 lanes x 2 f32 = 2 KB
    float* rb = ored + (wg * 64 + l) * 32;
    float* sb = rred + (wg * 64 + l) * 2;
    if (wh == 1) {
#pragma unroll
      for (int nt = 0; nt < 2; ++nt)
#pragma unroll
        for (int mt = 0; mt < 4; ++mt) {
          int idx = nt * 4 + mt;
          *(f32x4*)(rb + ((unsigned)(idx ^ (l & 7)) * 4)) = o[nt][mt];
        }
      sb[0] = rs[0];
      sb[1] = rs[1];
    }
    __syncthreads();
    if (wh == 1) return;
#pragma unroll
    for (int nt = 0; nt < 2; ++nt)
#pragma unroll
      for (int mt = 0; mt < 4; ++mt) {
        int idx = nt * 4 + mt;
        f32x4 pv = *(const f32x4*)(rb + ((unsigned)(idx ^ (l & 7)) * 4));
        o[nt][mt] += pv;
      }
    rs[0] += sb[0];
    rs[1] += sb[1];
  }

  // --- epilogue: reduce l over lane groups, normalize, store bf16 ctx
#pragma unroll
  for (int nt = 0; nt < 2; ++nt) {
    float lsum = rs[nt];
    lsum += __shfl_xor(lsum, 16, 64);
    lsum += __shfl_xor(lsum, 32, 64);
    float inv = 1.f / lsum;
    int srow = qt * 128 + wg * 32 + nt * 16 + ln;
    unsigned short* cb = ctx + (size_t)(b * SS + srow) * DD + h * HD;
#pragma unroll
    for (int mt = 0; mt < 4; ++mt) {
      ushort4 u4;
      u4.x = f2bf(o[nt][mt][0] * inv);
      u4.y = f2bf(o[nt][mt][1] * inv);
      u4.z = f2bf(o[nt][mt][2] * inv);
      u4.w = f2bf(o[nt][mt][3] * inv);
      *(ushort4*)(cb + mt * 16 + 4 * g) = u4;
    }
  }
}

// ---------------------------------------------------------------------------
extern "C" void kernel_launch(void* const* d_in, const int* in_sizes, int n_in,
                              void* d_out, int out_size, void* d_ws, size_t ws_size,
                              hipStream_t stream) {
  const float* x  = (const float*)d_in[0];
  const float* Wq = (const float*)d_in[1];
  const float* bq = (const float*)d_in[2];
  const float* Wk = (const float*)d_in[3];
  const float* bk = (const float*)d_in[4];
  const float* Wv = (const float*)d_in[5];
  const float* bv = (const float*)d_in[6];
  const float* Wo = (const float*)d_in[7];
  const float* bo = (const float*)d_in[8];
  float* out = (float*)d_out;

  const size_t ELEMS = (size_t)BB * SS * DD;  // 4,194,304
  char* ws = (char*)d_ws;
  unsigned short* xb   = (unsigned short*)ws;  ws += ELEMS * 2;
  unsigned short* WqT  = (unsigned short*)ws;  ws += (size_t)DD * DD * 2;
  unsigned short* WkT  = (unsigned short*)ws;  ws += (size_t)DD * DD * 2;
  unsigned short* WvT  = (unsigned short*)ws;  ws += (size_t)DD * DD * 2;
  unsigned short* WoT  = (unsigned short*)ws;  ws += (size_t)DD * DD * 2;
  unsigned short* Qb   = (unsigned short*)ws;  ws += ELEMS * 2;
  unsigned short* Kb   = (unsigned short*)ws;  ws += ELEMS * 2;
  unsigned short* VbT  = (unsigned short*)ws;  ws += ELEMS * 2;
  unsigned short* ctxb = (unsigned short*)ws;  ws += ELEMS * 2;

  // fused prep: x->bf16 (4096 blocks) + 4 weight transposes (4096 blocks)
  prep_kernel<<<8192, 256, 0, stream>>>(x, xb, Wq, WqT, Wk, WkT, Wv, WvT, Wo, WoT);

  qkv_gemm_mfma<<<768, 256, 0, stream>>>(xb, WqT, WkT, WvT, bq, bk, bv,
                                         Qb, Kb, VbT);

  dim3 attn_grid(BB * HH, SS / 128);           // (32, 16) = 512 blocks
  flash_attn_mfma<<<attn_grid, 512, 0, stream>>>(Qb, Kb, VbT, ctxb);

  out_gemm_mfma<<<256, 256, 0, stream>>>(ctxb, WoT, bo, out);
}

// Round 3
// 194.156 us; speedup vs baseline: 1.0825x; 1.0360x over previous
//
#include <hip/hip_runtime.h>
#include <hip/hip_bf16.h>

#define BB 2
#define SS 2048
#define DD 1024
#define HH 16
#define HD 64

typedef __attribute__((ext_vector_type(8))) short bf16x8;
typedef __attribute__((ext_vector_type(4))) float f32x4;

// round-to-nearest-even f32 -> bf16 (inputs finite)
__device__ __forceinline__ unsigned short f2bf(float f) {
  unsigned int u = __float_as_uint(f);
  return (unsigned short)((u + 0x7FFFu + ((u >> 16) & 1u)) >> 16);
}

// 2^x via hardware v_exp_f32
__device__ __forceinline__ float fast_exp2(float x) {
#if __has_builtin(__builtin_amdgcn_exp2f)
  return __builtin_amdgcn_exp2f(x);
#else
  return __expf(x * 0.6931471805599453f);
#endif
}

__device__ __forceinline__ void async_copy16(const unsigned short* gp, unsigned short* lp) {
  __builtin_amdgcn_global_load_lds(
      (const __attribute__((address_space(1))) unsigned int*)gp,
      (__attribute__((address_space(3))) unsigned int*)lp, 16, 0, 0);
}

// gfx950 cross-lane register swaps (VALU, not DS pipe).
__device__ __forceinline__ void pl32_swap(unsigned& a, unsigned& b) {
#if __has_builtin(__builtin_amdgcn_permlane32_swap)
  auto r = __builtin_amdgcn_permlane32_swap(a, b, false, false);
  a = r[0];
  b = r[1];
#else
  asm volatile("v_permlane32_swap_b32 %0, %1" : "+v"(a), "+v"(b));
#endif
}
__device__ __forceinline__ void pl16_swap(unsigned& a, unsigned& b) {
#if __has_builtin(__builtin_amdgcn_permlane16_swap)
  auto r = __builtin_amdgcn_permlane16_swap(a, b, false, false);
  a = r[0];
  b = r[1];
#else
  asm volatile("v_permlane16_swap_b32 %0, %1" : "+v"(a), "+v"(b));
#endif
}

// ---------------------------------------------------------------------------
// Fused prep: blocks [0,4096) convert x -> bf16; blocks [4096,8192) transpose
// one of the 4 weight matrices (1024 32x32 tiles each) to bf16 [N][K].
// ---------------------------------------------------------------------------
__global__ __launch_bounds__(256) void prep_kernel(
    const float* __restrict__ x, unsigned short* __restrict__ xb,
    const float* __restrict__ W0, unsigned short* __restrict__ T0,
    const float* __restrict__ W1, unsigned short* __restrict__ T1,
    const float* __restrict__ W2, unsigned short* __restrict__ T2,
    const float* __restrict__ W3, unsigned short* __restrict__ T3) {
  const int blk = blockIdx.x;
  const int t = threadIdx.x;
  if (blk < 4096) {
    int i = blk * 1024 + t * 4;
    float4 v = *(const float4*)(x + i);
    ushort4 u;
    u.x = f2bf(v.x); u.y = f2bf(v.y); u.z = f2bf(v.z); u.w = f2bf(v.w);
    *(ushort4*)(xb + i) = u;
    return;
  }
  const int j = blk - 4096;
  const int jw = j >> 10;          // which weight
  const int tb = j & 1023;
  const float* W = jw == 0 ? W0 : (jw == 1 ? W1 : (jw == 2 ? W2 : W3));
  unsigned short* T = jw == 0 ? T0 : (jw == 1 ? T1 : (jw == 2 ? T2 : T3));
  __shared__ float tile[32][33];
  int k0 = (tb & 31) * 32, n0 = (tb >> 5) * 32;
  int c = t & 31, r0 = t >> 5;
#pragma unroll
  for (int i = 0; i < 4; ++i) {
    int r = r0 + i * 8;
    tile[r][c] = W[(size_t)(k0 + r) * DD + n0 + c];
  }
  __syncthreads();
#pragma unroll
  for (int i = 0; i < 4; ++i) {
    int r = r0 + i * 8;
    T[(size_t)(n0 + r) * DD + k0 + c] = f2bf(tile[c][r]);
  }
}

// ---------------------------------------------------------------------------
// bf16 MFMA GEMM core (m97 single-buffer, BK=32): D = A[M,K]@B^T[N,K] + bias
// STORE=0: fp32 out [M][DD]   (used by out-projection only)
// ---------------------------------------------------------------------------
template <int STORE>
__device__ __forceinline__ void gemm_core(
    const unsigned short* __restrict__ A, const unsigned short* __restrict__ BT,
    const float* __restrict__ bias, void* __restrict__ outp, float scale,
    int bm, int bn) {
  const int t = threadIdx.x;
  const int w = t >> 6;
  const int l = t & 63;
  const int wm = (w >> 1) * 64;
  const int wn = (w & 1) * 64;

  __shared__ __align__(16) unsigned short As[128 * 32];
  __shared__ __align__(16) unsigned short Bs[128 * 32];

  f32x4 acc[4][4];
#pragma unroll
  for (int i = 0; i < 4; ++i)
#pragma unroll
    for (int j = 0; j < 4; ++j) acc[i][j] = (f32x4)0.f;

  const int fr = l & 15;
  const int kg = (l >> 4) * 8;

  for (int k0 = 0; k0 < DD; k0 += 32) {
    __syncthreads();
#pragma unroll
    for (int c = 0; c < 2; ++c) {
      int e = (w * 2 + c) * 512 + l * 8;
      int row = e >> 5, kk = e & 31;
      async_copy16(A + (size_t)(bm + row) * DD + k0 + kk, As + (w * 2 + c) * 512);
      async_copy16(BT + (size_t)(bn + row) * DD + k0 + kk, Bs + (w * 2 + c) * 512);
    }
    __syncthreads();

    bf16x8 af[4], bfr[4];
#pragma unroll
    for (int i = 0; i < 4; ++i)
      af[i] = *(const bf16x8*)(As + (wm + i * 16 + fr) * 32 + kg);
#pragma unroll
    for (int j = 0; j < 4; ++j)
      bfr[j] = *(const bf16x8*)(Bs + (wn + j * 16 + fr) * 32 + kg);
#pragma unroll
    for (int i = 0; i < 4; ++i)
#pragma unroll
      for (int j = 0; j < 4; ++j)
        acc[i][j] = __builtin_amdgcn_mfma_f32_16x16x32_bf16(af[i], bfr[j], acc[i][j], 0, 0, 0);
  }

  const int col_l = l & 15;
  const int row_l = (l >> 4) * 4;

#pragma unroll
  for (int i = 0; i < 4; ++i) {
    int m_base = bm + wm + i * 16 + row_l;
#pragma unroll
    for (int j = 0; j < 4; ++j) {
      int n = bn + wn + j * 16 + col_l;
      float bv = bias[n];
      float* out = (float*)outp;
#pragma unroll
      for (int r = 0; r < 4; ++r)
        out[(size_t)(m_base + r) * DD + n] = acc[i][j][r] + bv;
    }
  }
}

// output projection, 256 blocks, XCD-swizzled (8 bn per bm on one XCD)
__global__ __launch_bounds__(256) void out_gemm_mfma(
    const unsigned short* __restrict__ A, const unsigned short* __restrict__ WoT,
    const float* __restrict__ bo, float* __restrict__ out) {
  const int i = blockIdx.x;
  const int xcd = i & 7;
  const int slot = i >> 3;            // 0..31
  const int bm = (xcd + 8 * (slot >> 3)) * 128;
  const int bn = (slot & 7) * 128;
  gemm_core<0>(A, WoT, bo, (void*)out, 1.0f, bm, bn);
}

// ---------------------------------------------------------------------------
// QKV projection, 8-phase 256x256xBK64 template (T2+T3+T4+T5).
// R2 counters on the old 128^2 2-barrier core: MfmaUtil 18%, VALU 11%,
// HBM 19% -> exposed load latency at every K-step's vmcnt(0) drain.
// This kernel: 512 thr = 8 waves (2M x 4N), LDS 128 KiB =
// [A,B][dbuf2][khalf2][256x32] bf16. Per K-tile (BK=64): 4 phases
// (kh x mh), 16 MFMA each; per phase stage ONE half-tile (2 x
// global_load_lds dwordx4/thread) at skew 6 (used 6 phases later);
// vmcnt(4) ONLY at tile boundaries (2 half-tiles stay in flight across
// barriers, never drain-0 in the loop). Raw s_barrier + asm waitcnt so
// the compiler cannot insert its vmcnt(0) drain. Two-bit XOR swizzle
// (16B chunks: ^32B on row&8, ^16B on row&4) applied to BOTH the
// global source and the ds_read address -> 2-way (free) bank aliasing.
// Numerics: identical k-order accumulation to the old kernel.
// Grid: 192 blocks = 16 bm x (3 matrices x 4 bn), XCD-chunked.
// ---------------------------------------------------------------------------
#define QPHASE(DB, KH, MH, S, VM) do {                                        \
    bf16x8 af[4];                                                             \
    _Pragma("unroll")                                                         \
    for (int ii = 0; ii < 4; ++ii) {                                          \
      int row = wm * 128 + (MH) * 64 + ii * 16 + fr;                          \
      int kb = kg16 ^ ((row & 8) ? 32 : 0) ^ ((row & 4) ? 16 : 0);            \
      af[ii] = *(const bf16x8*)((const char*)&lds[0][DB][KH][0] + row * 64 + kb); \
    }                                                                         \
    if ((MH) == 0) {                                                          \
      _Pragma("unroll")                                                       \
      for (int j = 0; j < 4; ++j) {                                           \
        int row = wn * 64 + j * 16 + fr;                                      \
        int kb = kg16 ^ ((row & 8) ? 32 : 0) ^ ((row & 4) ? 16 : 0);          \
        bfr[j] = *(const bf16x8*)((const char*)&lds[1][DB][KH][0] + row * 64 + kb); \
      }                                                                       \
    }                                                                         \
    stage_half(S);                                                            \
    asm volatile("s_barrier" ::: "memory");                                   \
    __builtin_amdgcn_s_setprio(1);                                            \
    _Pragma("unroll")                                                         \
    for (int ii = 0; ii < 4; ++ii)                                            \
      _Pragma("unroll")                                                       \
      for (int j = 0; j < 4; ++j)                                             \
        acc[(MH) * 4 + ii][j] = __builtin_amdgcn_mfma_f32_16x16x32_bf16(      \
            af[ii], bfr[j], acc[(MH) * 4 + ii][j], 0, 0, 0);                  \
    __builtin_amdgcn_s_setprio(0);                                            \
    if ((VM) == 1) asm volatile("s_waitcnt vmcnt(4)" ::: "memory");           \
    if ((VM) == 2) asm volatile("s_waitcnt vmcnt(0)" ::: "memory");           \
    asm volatile("s_barrier" ::: "memory");                                   \
  } while (0)

__global__ __launch_bounds__(512, 2) void qkv_gemm_8ph(
    const unsigned short* __restrict__ A,
    const unsigned short* __restrict__ WqT, const unsigned short* __restrict__ WkT,
    const unsigned short* __restrict__ WvT,
    const float* __restrict__ bq, const float* __restrict__ bk,
    const float* __restrict__ bv,
    unsigned short* __restrict__ Qo, unsigned short* __restrict__ Ko,
    unsigned short* __restrict__ VTo) {
  const int i = blockIdx.x;
  const int xcd = i & 7;
  const int slot = i >> 3;              // 0..23
  const int bmi = xcd * 2 + (slot / 12);
  const int c = slot % 12;
  const int which = c >> 2;             // 0:Q 1:K 2:V
  const int bm = bmi * 256;
  const int bn = (c & 3) * 256;
  const unsigned short* BT = which == 0 ? WqT : (which == 1 ? WkT : WvT);
  const float* bias = which == 0 ? bq : (which == 1 ? bk : bv);

  const int t = threadIdx.x;
  const int w = t >> 6;
  const int l = t & 63;
  const int wm = w >> 2;        // 0..1 (M)
  const int wn = w & 3;         // 0..3 (N)
  const int fr = l & 15;
  const int kg16 = (l >> 4) * 16;   // byte offset of lane's k-group in 32k half

  // [mat A/B][dbuf][khalf][256 rows x 32 k] bf16, 128 KiB total
  __shared__ __align__(16) unsigned short lds[2][2][2][8192];

  f32x4 acc[8][4];
#pragma unroll
  for (int mi = 0; mi < 8; ++mi)
#pragma unroll
    for (int j = 0; j < 4; ++j) acc[mi][j] = (f32x4)0.f;

  // stage half-tile s (s = 4*T + {0:A_k0,1:B_k0,2:A_k1,3:B_k1}); 2 loads/thr
  auto stage_half = [&](int s) {
    if (s >= 64) return;
    const int Ts = s >> 2;
    const int db = Ts & 1;
    const int typ = s & 3;
    const int kh = typ >> 1;
    const int isB = typ & 1;
    const unsigned short* src = isB ? BT : A;
    const int rbase = isB ? bn : bm;
    unsigned short* dstbase = &lds[isB][db][kh][0];
    const int k0 = Ts * 64 + kh * 32;
#pragma unroll
    for (int j = 0; j < 2; ++j) {
      int cc = (w * 2 + j) * 64 + l;    // 16B chunk 0..1023
      int row = cc >> 2;
      int ke = ((cc & 3) * 8) ^ ((row & 8) ? 16 : 0) ^ ((row & 4) ? 8 : 0);
      async_copy16(src + (size_t)(rbase + row) * DD + k0 + ke,
                   dstbase + (w * 2 + j) * 512);
    }
  };

  bf16x8 bfr[4];

  // prologue: tile0 (4 halves) + tile1 first 2 halves; wait tile0 landed
  for (int s = 0; s < 6; ++s) stage_half(s);
  asm volatile("s_waitcnt vmcnt(4)" ::: "memory");
  asm volatile("s_barrier" ::: "memory");

  for (int T = 0; T < 14; ++T) {
    const int db = T & 1;
    const int sb = 4 * T + 6;
    QPHASE(db, 0, 0, sb + 0, 0);
    QPHASE(db, 0, 1, sb + 1, 0);
    QPHASE(db, 1, 0, sb + 2, 0);
    QPHASE(db, 1, 1, sb + 3, 1);      // boundary: vmcnt(4)
  }
  // T = 14 (db 0): stages s=62,63 then exhausted; final drain at boundary
  QPHASE(0, 0, 0, 62, 0);
  QPHASE(0, 0, 1, 63, 0);
  QPHASE(0, 1, 0, 64, 0);
  QPHASE(0, 1, 1, 64, 2);             // vmcnt(0): everything landed
  // T = 15 (db 1): no staging, no waits needed
  QPHASE(1, 0, 0, 64, 0);
  QPHASE(1, 0, 1, 64, 0);
  QPHASE(1, 1, 0, 64, 0);
  QPHASE(1, 1, 1, 64, 0);

  const int col_l = l & 15;
  const int row_l = (l >> 4) * 4;
  const int b_ = bm >> 11;

  if (which != 2) {
    // Q/K: bf16 out [B,H,S,HD], scaled
    const float scl = which == 0 ? 0.18033688011112042f : 1.0f;
    unsigned short* out = which == 0 ? Qo : Ko;
#pragma unroll
    for (int mi = 0; mi < 8; ++mi) {
      int m_base = bm + wm * 128 + mi * 16 + row_l;
#pragma unroll
      for (int j = 0; j < 4; ++j) {
        int n = bn + wn * 64 + j * 16 + col_l;
        float bv = bias[n];
        int h_ = n >> 6, hd_ = n & 63;
#pragma unroll
        for (int r = 0; r < 4; ++r) {
          int m = m_base + r;
          int b2 = m >> 11, s_ = m & 2047;
          out[(((size_t)(b2 * HH + h_) * SS) + s_) * HD + hd_] =
              f2bf((acc[mi][j][r] + bv) * scl);
        }
      }
    }
  } else {
    // V: transpose 256x256 C tile via LDS -> VTo[(b*HH+h)*HD+hd][s]
    unsigned int* Tt = (unsigned int*)&lds[0][0][0][0];  // 32768 dwords
#pragma unroll
    for (int mi = 0; mi < 8; ++mi) {
      int m2a = wm * 64 + mi * 8 + (l >> 4) * 2;  // dword index (m pair), even
#pragma unroll
      for (int j = 0; j < 4; ++j) {
        int n = wn * 64 + j * 16 + col_l;
        float bv = bias[bn + n];
        uint2 dd;
        dd.x = (unsigned)f2bf(acc[mi][j][0] + bv) |
               ((unsigned)f2bf(acc[mi][j][1] + bv) << 16);
        dd.y = (unsigned)f2bf(acc[mi][j][2] + bv) |
               ((unsigned)f2bf(acc[mi][j][3] + bv) << 16);
        *(uint2*)(Tt + n * 128 + (m2a ^ ((n & 7) << 2))) = dd;
      }
    }
    __syncthreads();
    const int srow0 = bm & 2047;
    const int n_r = t >> 1;
    const int half = t & 1;
    const int n_glob = bn + n_r;
    const int h_ = n_glob >> 6, hd_ = n_glob & 63;
    unsigned short* ob =
        VTo + ((size_t)((b_ * HH + h_) * HD + hd_)) * SS + srow0 + half * 128;
#pragma unroll
    for (int cp = 0; cp < 16; ++cp) {
      uint4 v = *(const uint4*)(Tt + n_r * 128 +
                                ((half * 64 + cp * 4) ^ ((n_r & 7) << 2)));
      *(uint4*)(ob + cp * 8) = v;
    }
  }
}

// ---------------------------------------------------------------------------
// MFMA flash attention v8 (unchanged from R2, passed): Q-tile 128, 8 waves
// (4 q-subtiles x 2 key-parities), dbuf K/V, permlane P redistribution,
// cross-parity LDS combine.
// ---------------------------------------------------------------------------
__global__ __launch_bounds__(512, 4) void flash_attn_mfma(
    const unsigned short* __restrict__ Q,   // [B,H,S,HD] bf16 (pre-scaled)
    const unsigned short* __restrict__ K,   // [B,H,S,HD] bf16
    const unsigned short* __restrict__ VT,  // [B,H,HD,S] bf16
    unsigned short* __restrict__ ctx) {     // [B,S,D] bf16
  const int bh = blockIdx.x;
  const int qt = blockIdx.y;
  const int b  = bh >> 4;
  const int h  = bh & 15;
  const int t  = threadIdx.x;
  const int w  = t >> 6;   // wave 0..7
  const int l  = t & 63;
  const int wg = w & 3;    // q sub-tile 0..3
  const int wh = w >> 2;   // key-tile parity 0/1
  const int g  = l >> 4;   // lane group 0..3
  const int ln = l & 15;   // q index within n-tile

  const unsigned short* Qp = Q + ((size_t)bh * SS + (size_t)qt * 128 + wg * 32) * HD;
  const unsigned short* Kp = K + (size_t)bh * SS * HD;
  const unsigned short* Vp = VT + (size_t)bh * HD * SS;

  __shared__ __align__(16) unsigned short Ks[2][2][64 * 64];  // [parity][dbuf] swz
  __shared__ __align__(16) unsigned short Vs[2][2][64 * 64];  // [parity][dbuf] swz

  bf16x8 qf[2][2];
#pragma unroll
  for (int nt = 0; nt < 2; ++nt)
#pragma unroll
    for (int kb = 0; kb < 2; ++kb)
      qf[nt][kb] = *(const bf16x8*)(Qp + (nt * 16 + ln) * HD + kb * 32 + g * 8);

  f32x4 o[2][4];
#pragma unroll
  for (int nt = 0; nt < 2; ++nt)
#pragma unroll
    for (int mt = 0; mt < 4; ++mt) o[nt][mt] = (f32x4)0.f;
  float rs[2] = {0.f, 0.f};

  auto stage2 = [&](int kt2, int db) {
    const int cidx = t;
    const int row = cidx >> 3, cc = cidx & 7;
    const int gcc = cc ^ (row & 7);
    const int k0 = kt2 * 128;
    async_copy16(Kp + (size_t)(k0 + row) * HD + gcc * 8, &Ks[0][db][w * 512]);
    async_copy16(Kp + (size_t)(k0 + 64 + row) * HD + gcc * 8, &Ks[1][db][w * 512]);
    async_copy16(Vp + (size_t)row * SS + k0 + gcc * 8, &Vs[0][db][w * 512]);
    async_copy16(Vp + (size_t)row * SS + k0 + 64 + gcc * 8, &Vs[1][db][w * 512]);
  };

  stage2(0, 0);
  for (int kt2 = 0; kt2 < SS / 128; ++kt2) {
    const int db = kt2 & 1;
    __syncthreads();
    if (kt2 + 1 < SS / 128) stage2(kt2 + 1, db ^ 1);

    const unsigned short* Kst = &Ks[wh][db][0];
    const unsigned short* Vst = &Vs[wh][db][0];

    f32x4 st[2][4];
#pragma unroll
    for (int nt = 0; nt < 2; ++nt)
#pragma unroll
      for (int mt = 0; mt < 4; ++mt) st[nt][mt] = (f32x4)0.f;
#pragma unroll
    for (int kb = 0; kb < 2; ++kb)
#pragma unroll
      for (int mt = 0; mt < 4; ++mt) {
        int row = mt * 16 + ln;
        bf16x8 ka = *(const bf16x8*)(&Kst[row * 64 + (((kb * 4 + g) ^ (row & 7)) * 8)]);
        st[0][mt] = __builtin_amdgcn_mfma_f32_16x16x32_bf16(ka, qf[0][kb], st[0][mt], 0, 0, 0);
        st[1][mt] = __builtin_amdgcn_mfma_f32_16x16x32_bf16(ka, qf[1][kb], st[1][mt], 0, 0, 0);
      }

    unsigned Sd[2][4][2];
#pragma unroll
    for (int nt = 0; nt < 2; ++nt) {
#pragma unroll
      for (int mt = 0; mt < 4; ++mt) {
        float p0 = fast_exp2(st[nt][mt][0]);
        float p1 = fast_exp2(st[nt][mt][1]);
        float p2 = fast_exp2(st[nt][mt][2]);
        float p3 = fast_exp2(st[nt][mt][3]);
        Sd[nt][mt][0] = __builtin_amdgcn_perm(__float_as_uint(p1), __float_as_uint(p0),
                                              0x07060302u);
        Sd[nt][mt][1] = __builtin_amdgcn_perm(__float_as_uint(p3), __float_as_uint(p2),
                                              0x07060302u);
        rs[nt] += (p0 + p1) + (p2 + p3);
      }
#pragma unroll
      for (int m1 = 0; m1 < 2; ++m1)
#pragma unroll
        for (int p = 0; p < 2; ++p)
          pl32_swap(Sd[nt][2 * m1][p], Sd[nt][2 * m1 + 1][p]);
#pragma unroll
      for (int m1 = 0; m1 < 2; ++m1)
#pragma unroll
        for (int p = 0; p < 2; ++p)
          pl16_swap(Sd[nt][2 * m1][p], Sd[nt][2 * m1 + 1][p]);
    }

#pragma unroll
    for (int kb = 0; kb < 2; ++kb) {
      bf16x8 pbv[2];
#pragma unroll
      for (int nt = 0; nt < 2; ++nt) {
        union { unsigned u[4]; bf16x8 v; } cu;
        cu.u[0] = Sd[nt][2 * kb][0];
        cu.u[1] = Sd[nt][2 * kb][1];
        cu.u[2] = Sd[nt][2 * kb + 1][0];
        cu.u[3] = Sd[nt][2 * kb + 1][1];
        pbv[nt] = cu.v;
      }
#pragma unroll
      for (int mt = 0; mt < 4; ++mt) {
        int row = mt * 16 + ln;
        bf16x8 va = *(const bf16x8*)(&Vst[row * 64 + (((kb * 4 + g) ^ (row & 7)) * 8)]);
        o[0][mt] = __builtin_amdgcn_mfma_f32_16x16x32_bf16(va, pbv[0], o[0][mt], 0, 0, 0);
        o[1][mt] = __builtin_amdgcn_mfma_f32_16x16x32_bf16(va, pbv[1], o[1][mt], 0, 0, 0);
      }
    }
  }

  __syncthreads();
  {
    float* ored = (float*)&Vs[0][0][0];
    float* rred = (float*)&Ks[0][0][0];
    float* rb = ored + (wg * 64 + l) * 32;
    float* sb = rred + (wg * 64 + l) * 2;
    if (wh == 1) {
#pragma unroll
      for (int nt = 0; nt < 2; ++nt)
#pragma unroll
        for (int mt = 0; mt < 4; ++mt) {
          int idx = nt * 4 + mt;
          *(f32x4*)(rb + ((unsigned)(idx ^ (l & 7)) * 4)) = o[nt][mt];
        }
      sb[0] = rs[0];
      sb[1] = rs[1];
    }
    __syncthreads();
    if (wh == 1) return;
#pragma unroll
    for (int nt = 0; nt < 2; ++nt)
#pragma unroll
      for (int mt = 0; mt < 4; ++mt) {
        int idx = nt * 4 + mt;
        f32x4 pv = *(const f32x4*)(rb + ((unsigned)(idx ^ (l & 7)) * 4));
        o[nt][mt] += pv;
      }
    rs[0] += sb[0];
    rs[1] += sb[1];
  }

#pragma unroll
  for (int nt = 0; nt < 2; ++nt) {
    float lsum = rs[nt];
    lsum += __shfl_xor(lsum, 16, 64);
    lsum += __shfl_xor(lsum, 32, 64);
    float inv = 1.f / lsum;
    int srow = qt * 128 + wg * 32 + nt * 16 + ln;
    unsigned short* cb = ctx + (size_t)(b * SS + srow) * DD + h * HD;
#pragma unroll
    for (int mt = 0; mt < 4; ++mt) {
      ushort4 u4;
      u4.x = f2bf(o[nt][mt][0] * inv);
      u4.y = f2bf(o[nt][mt][1] * inv);
      u4.z = f2bf(o[nt][mt][2] * inv);
      u4.w = f2bf(o[nt][mt][3] * inv);
      *(ushort4*)(cb + mt * 16 + 4 * g) = u4;
    }
  }
}

// ---------------------------------------------------------------------------
extern "C" void kernel_launch(void* const* d_in, const int* in_sizes, int n_in,
                              void* d_out, int out_size, void* d_ws, size_t ws_size,
                              hipStream_t stream) {
  const float* x  = (const float*)d_in[0];
  const float* Wq = (const float*)d_in[1];
  const float* bq = (const float*)d_in[2];
  const float* Wk = (const float*)d_in[3];
  const float* bk = (const float*)d_in[4];
  const float* Wv = (const float*)d_in[5];
  const float* bv = (const float*)d_in[6];
  const float* Wo = (const float*)d_in[7];
  const float* bo = (const float*)d_in[8];
  float* out = (float*)d_out;

  const size_t ELEMS = (size_t)BB * SS * DD;  // 4,194,304
  char* ws = (char*)d_ws;
  unsigned short* xb   = (unsigned short*)ws;  ws += ELEMS * 2;
  unsigned short* WqT  = (unsigned short*)ws;  ws += (size_t)DD * DD * 2;
  unsigned short* WkT  = (unsigned short*)ws;  ws += (size_t)DD * DD * 2;
  unsigned short* WvT  = (unsigned short*)ws;  ws += (size_t)DD * DD * 2;
  unsigned short* WoT  = (unsigned short*)ws;  ws += (size_t)DD * DD * 2;
  unsigned short* Qb   = (unsigned short*)ws;  ws += ELEMS * 2;
  unsigned short* Kb   = (unsigned short*)ws;  ws += ELEMS * 2;
  unsigned short* VbT  = (unsigned short*)ws;  ws += ELEMS * 2;
  unsigned short* ctxb = (unsigned short*)ws;  ws += ELEMS * 2;

  prep_kernel<<<8192, 256, 0, stream>>>(x, xb, Wq, WqT, Wk, WkT, Wv, WvT, Wo, WoT);

  qkv_gemm_8ph<<<192, 512, 0, stream>>>(xb, WqT, WkT, WvT, bq, bk, bv,
                                        Qb, Kb, VbT);

  dim3 attn_grid(BB * HH, SS / 128);           // (32, 16) = 512 blocks
  flash_attn_mfma<<<attn_grid, 512, 0, stream>>>(Qb, Kb, VbT, ctxb);

  out_gemm_mfma<<<256, 256, 0, stream>>>(ctxb, WoT, bo, out);
}